// Round 8
// baseline (341.156 us; speedup 1.0000x reference)
//
#include <hip/hip_runtime.h>

#define BB 16      // batch
#define SS 48      // seq len
#define VV 16000   // vocab
#define DD 128     // embed
#define NC (DD / 4)           // 32 float4 chunks per row — ALL loops derive from this
#define TV 64                 // vocab rows per tile (lane = row)
#define TCH (TV * NC)         // 2048 chunks = 32 KB per tile
#define NTHREADS 128          // 2 waves: wave0 -> batches 0-7, wave1 -> 8-15
#define LPT (TCH / NTHREADS)  // 16 global_load_lds per thread per tile
#define TPB 5                 // tiles per block
#define BPS (VV / TV / TPB)   // 50 blocks per s  (50*5*64 = 16000 exactly)

constexpr float EPS   = 1e-8f;
constexpr float SCALE = 10.0f;

typedef unsigned int u32;
#define GAS __attribute__((address_space(1)))
#define LAS __attribute__((address_space(3)))

// Kernel 1 (unchanged, verified R2-R7): per-batch causal prefix context,
// normalized. One block = one batch, 64 threads. ctx_n layout [S][B][D].
__global__ __launch_bounds__(64) void ctx_kernel(
    const int*   __restrict__ tokens,   // [B,S]
    const float* __restrict__ scalars,  // [S,V]
    const float* __restrict__ wvecs,    // [S,V,D]
    float*       __restrict__ ctx_n)    // [S,B,D]
{
    const int b    = blockIdx.x;
    const int lane = threadIdx.x;  // 0..63

    float a[SS], w0[SS], w1[SS];
    #pragma unroll
    for (int s = 0; s < SS; ++s) {
        const int tok = tokens[b * SS + s];
        a[s] = scalars[(size_t)s * VV + tok];
        const float* wp = wvecs + ((size_t)s * VV + tok) * DD;
        w0[s] = wp[lane];
        w1[s] = wp[lane + 64];
    }

    float run0 = 0.f, run1 = 0.f;
    #pragma unroll
    for (int s = 0; s < SS; ++s) {
        float p = fmaf(run0, run0, run1 * run1);
        #pragma unroll
        for (int off = 32; off > 0; off >>= 1)
            p += __shfl_xor(p, off);
        const float denom = fmaxf(sqrtf(p), EPS);  // torch F.normalize semantics
        float* o = ctx_n + ((size_t)s * BB + b) * DD;
        o[lane]      = run0 / denom;
        o[lane + 64] = run1 / denom;
        run0 = fmaf(a[s], w0[s], run0);   // position s contributes to positions > s
        run1 = fmaf(a[s], w1[s], run1);
    }
}

// Stage one 64x512B tile via global_load_lds (no VGPR round-trip -> nothing
// to spill). LDS dest is LINEAR (hardware requirement); the GLOBAL source is
// pre-swizzled (rule #21): LDS slot i=(r,c) receives global chunk (r, c^(r&7)).
// The XOR stays within each row's aligned 8-chunk (128B) group, so every
// wave-instruction still covers the same contiguous 1KB window -> coalesced.
__device__ __forceinline__ void stage_tile(const float4* __restrict__ tsrc,
                                           float4* lbuf, int tid)
{
    #pragma unroll
    for (int k = 0; k < LPT; ++k) {
        const int i  = tid + k * NTHREADS;                        // linear LDS slot
        const int gi = (i & ~31) | ((i & 31) ^ ((i >> 5) & 7));   // swizzled source
        __builtin_amdgcn_global_load_lds((const GAS u32*)(tsrc + gi),
                                         (LAS u32*)(lbuf + i), 16, 0, 0);
    }
}

// Kernel 2: out[b,s,v] = SCALE * dot(ctx_n[b,s,:], emb[s,v,:]) / max(||emb[s,v,:]||, eps)
//
// lane = row (each ds_read_b128 carries 1KB distinct data); read chunk
// cp = j ^ (row&7): at fixed j the 64 lanes spread evenly over all 8
// bank-groups (8 lanes each, distinct rows) = conflict-free minimum, while
// the LOGICAL chunk j stays wave-uniform so ctx loads take the scalar path.
// Double-buffered with counted vmcnt (T4): raw s_barrier, never vmcnt(0)
// mid-loop, so tile t+1 streams from HBM while tile t computes.
__global__ __launch_bounds__(NTHREADS) void logits_kernel(
    const float* __restrict__ ctx_n,  // [S,B,D] (normalized)
    const float* __restrict__ emb,    // [S,V,D]
    float*       __restrict__ out)    // [B,S,V]
{
    const int s     = blockIdx.y;
    const int tile0 = blockIdx.x * TPB;
    const int tid   = threadIdx.x;       // 0..127
    const int row   = tid & 63;          // this lane's row within the tile
    const int rx    = row & 7;           // read-side XOR key
    const int wu    = __builtin_amdgcn_readfirstlane(tid >> 6);  // wave id (uniform)

    __shared__ float4 lds[2 * TCH];      // 2 x 32 KB double buffer

    const float4* ebase = (const float4*)emb + (size_t)s * VV * NC;
    // this wave's 8 batches; uniform pointer -> s_load path, zero LDS traffic
    const float4* cw = (const float4*)ctx_n + ((size_t)s * BB + wu * 8) * NC;

    stage_tile(ebase + (size_t)tile0 * TCH, &lds[0], tid);

    int cur = 0;
    for (int t = 0; t < TPB; ++t) {
        if (t + 1 < TPB) {
            stage_tile(ebase + (size_t)(tile0 + t + 1) * TCH, &lds[(cur ^ 1) * TCH], tid);
            asm volatile("s_waitcnt vmcnt(16)" ::: "memory");  // drain tile t only
        } else {
            asm volatile("s_waitcnt vmcnt(0)" ::: "memory");
        }
        __builtin_amdgcn_s_barrier();    // raw: no implicit vmcnt(0) drain

        const float4* lrow = &lds[cur * TCH + row * NC];
        float acc[8];
        #pragma unroll
        for (int bb = 0; bb < 8; ++bb) acc[bb] = 0.f;
        float pn = 0.f;

        #pragma unroll 8
        for (int j = 0; j < NC; ++j) {
            const float4 e = lrow[j ^ rx];       // conflict-free swizzled read
            pn = fmaf(e.x, e.x, pn);
            pn = fmaf(e.y, e.y, pn);
            pn = fmaf(e.z, e.z, pn);
            pn = fmaf(e.w, e.w, pn);
            #pragma unroll
            for (int bb = 0; bb < 8; ++bb) {
                const float4 c = cw[bb * NC + j];  // uniform j -> scalar path
                acc[bb] = fmaf(e.x, c.x, acc[bb]);
                acc[bb] = fmaf(e.y, c.y, acc[bb]);
                acc[bb] = fmaf(e.z, c.z, acc[bb]);
                acc[bb] = fmaf(e.w, c.w, acc[bb]);
            }
        }

        // Epilogue: coalesced stores (lane-consecutive v), 8 per wave.
        const int v = (tile0 + t) * TV + row;
        const float f = SCALE / fmaxf(sqrtf(pn), EPS);  // F.normalize semantics
        #pragma unroll
        for (int bb = 0; bb < 8; ++bb)
            out[((size_t)(wu * 8 + bb) * SS + s) * VV + v] = acc[bb] * f;

        __builtin_amdgcn_s_barrier();    // all reads of lds[cur] done before overwrite
        cur ^= 1;
    }
}

extern "C" void kernel_launch(void* const* d_in, const int* in_sizes, int n_in,
                              void* d_out, int out_size, void* d_ws, size_t ws_size,
                              hipStream_t stream) {
    const int*   tokens  = (const int*)d_in[0];
    const float* scalars = (const float*)d_in[1];
    const float* wvecs   = (const float*)d_in[2];
    const float* emb     = (const float*)d_in[3];
    float*       out     = (float*)d_out;
    float*       ctx_n   = (float*)d_ws;   // S*B*D*4 = 393,216 bytes

    ctx_kernel<<<dim3(BB), dim3(64), 0, stream>>>(tokens, scalars, wvecs, ctx_n);

    dim3 grid(BPS, SS);   // (50, 48) = 2400 blocks, 128 threads each
    logits_kernel<<<grid, dim3(NTHREADS), 0, stream>>>(ctx_n, emb, out);
}

// Round 9
// 183.418 us; speedup vs baseline: 1.8600x; 1.8600x over previous
//
#include <hip/hip_runtime.h>

#define BB 16      // batch
#define SS 48      // seq len
#define VV 16000   // vocab
#define DD 128     // embed
#define NC (DD / 4)           // 32 float4 chunks per row — ALL loops derive from this
#define TV 64                 // vocab rows per tile (lane = row)
#define TCH (TV * NC)         // 2048 chunks = 32 KB per tile
#define NT 256                // 4 waves; wave w -> batches 4w..4w+3
#define NW 4
#define BPW (BB / NW)         // 4 batches per wave
#define LPT (TCH / NT)        // 8 global_load_lds per thread per tile
#define TPB 5                 // tiles per block
#define BPS (VV / TV / TPB)   // 50 blocks per s

constexpr float EPS   = 1e-8f;
constexpr float SCALE = 10.0f;

typedef unsigned int u32;
#define GAS __attribute__((address_space(1)))
#define LAS __attribute__((address_space(3)))

// Kernel 1 (unchanged, verified R2-R8): per-batch causal prefix context,
// normalized. One block = one batch, 64 threads. ctx_n layout [S][B][D].
__global__ __launch_bounds__(64) void ctx_kernel(
    const int*   __restrict__ tokens,   // [B,S]
    const float* __restrict__ scalars,  // [S,V]
    const float* __restrict__ wvecs,    // [S,V,D]
    float*       __restrict__ ctx_n)    // [S,B,D]
{
    const int b    = blockIdx.x;
    const int lane = threadIdx.x;  // 0..63

    float a[SS], w0[SS], w1[SS];
    #pragma unroll
    for (int s = 0; s < SS; ++s) {
        const int tok = tokens[b * SS + s];
        a[s] = scalars[(size_t)s * VV + tok];
        const float* wp = wvecs + ((size_t)s * VV + tok) * DD;
        w0[s] = wp[lane];
        w1[s] = wp[lane + 64];
    }

    float run0 = 0.f, run1 = 0.f;
    #pragma unroll
    for (int s = 0; s < SS; ++s) {
        float p = fmaf(run0, run0, run1 * run1);
        #pragma unroll
        for (int off = 32; off > 0; off >>= 1)
            p += __shfl_xor(p, off);
        const float denom = fmaxf(sqrtf(p), EPS);  // torch F.normalize semantics
        float* o = ctx_n + ((size_t)s * BB + b) * DD;
        o[lane]      = run0 / denom;
        o[lane + 64] = run1 / denom;
        run0 = fmaf(a[s], w0[s], run0);   // position s contributes to positions > s
        run1 = fmaf(a[s], w1[s], run1);
    }
}

// Stage one 64x512B emb tile via global_load_lds (no VGPR round-trip).
// LDS dest LINEAR (hardware requirement); GLOBAL source pre-swizzled:
// LDS slot (r,c) <- global chunk (r, c ^ (r&7)). XOR stays inside each row's
// 512B, so every wave instruction still covers one contiguous 1KB window.
__device__ __forceinline__ void stage_tile(const float4* __restrict__ tsrc,
                                           float4* lbuf, int tid)
{
    #pragma unroll
    for (int k = 0; k < LPT; ++k) {
        const int i  = tid + k * NT;                              // linear LDS slot
        const int gi = (i & ~31) | ((i & 31) ^ ((i >> 5) & 7));   // swizzled source
        __builtin_amdgcn_global_load_lds((const GAS u32*)(tsrc + gi),
                                         (LAS u32*)(lbuf + i), 16, 0, 0);
    }
}

// One tile's compute+store. emb read lane=row (swizzled, distinct 1KB/inst);
// ctx read as wave-uniform ds_read_b128 broadcasts (lgkmcnt domain — never
// touches the vmcnt FIFO that the stage pipeline counts on).
__device__ __forceinline__ void tile_body(const float4* __restrict__ embbuf,
                                          const float4* __restrict__ ctxw,
                                          float* __restrict__ out,
                                          int s, int vbase, int row, int rx, int wb)
{
    const float4* lrow = embbuf + row * NC;
    float acc[BPW];
    #pragma unroll
    for (int bb = 0; bb < BPW; ++bb) acc[bb] = 0.f;
    float pn = 0.f;

    #pragma unroll 8
    for (int j = 0; j < NC; ++j) {
        const float4 e = lrow[j ^ rx];          // swizzled LDS read
        pn = fmaf(e.x, e.x, pn);
        pn = fmaf(e.y, e.y, pn);
        pn = fmaf(e.z, e.z, pn);
        pn = fmaf(e.w, e.w, pn);
        #pragma unroll
        for (int bb = 0; bb < BPW; ++bb) {
            const float4 c = ctxw[bb * NC + j]; // wave-uniform -> LDS broadcast
            acc[bb] = fmaf(e.x, c.x, acc[bb]);
            acc[bb] = fmaf(e.y, c.y, acc[bb]);
            acc[bb] = fmaf(e.z, c.z, acc[bb]);
            acc[bb] = fmaf(e.w, c.w, acc[bb]);
        }
    }

    const int v = vbase + row;
    const float f = SCALE / fmaxf(sqrtf(pn), EPS);  // F.normalize semantics
    #pragma unroll
    for (int bb = 0; bb < BPW; ++bb)
        out[((size_t)(wb + bb) * SS + s) * VV + v] = acc[bb] * f;
}

// Kernel 2: out[b,s,v] = SCALE * dot(ctx_n[b,s,:], emb[s,v,:]) / max(||emb[s,v,:]||, eps)
// Double-buffered global_load_lds pipeline with counted vmcnt (T4); per-wave
// FIFO carries ONLY stage loads (8/tile) and output stores (4/tile):
//   t=0: [stage0:8][stage1:8]             -> vmcnt(8)
//   t=1..3: [stage t:8][stores:4][next:8] -> vmcnt(12)
//   t=4: [stage4:8][stores:4]             -> vmcnt(4)
__global__ __launch_bounds__(NT) void logits_kernel(
    const float* __restrict__ ctx_n,  // [S,B,D] (normalized)
    const float* __restrict__ emb,    // [S,V,D]
    float*       __restrict__ out)    // [B,S,V]
{
    const int s     = blockIdx.y;
    const int tile0 = blockIdx.x * TPB;
    const int tid   = threadIdx.x;       // 0..255
    const int row   = tid & 63;
    const int rx    = row & 7;
    const int wu    = __builtin_amdgcn_readfirstlane(tid >> 6);  // wave id (uniform)
    const int wb    = wu * BPW;          // this wave's first batch

    __shared__ float4 embL[2 * TCH];     // 64 KB double buffer
    __shared__ float4 ctxL[BB * NC];     // 8 KB ctx slice for this s

    // Stage ctx once (512 float4, 2 per thread), then full drain: the vmcnt
    // FIFO is clean before the stage pipeline starts.
    const float4* csrc = (const float4*)ctx_n + (size_t)s * BB * NC;
    ctxL[tid]      = csrc[tid];
    ctxL[tid + NT] = csrc[tid + NT];
    __syncthreads();

    const float4* ebase = (const float4*)emb + (size_t)s * VV * NC;
    const float4* ctxw  = &ctxL[wb * NC];

    stage_tile(ebase + (size_t)(tile0 + 0) * TCH, &embL[0], tid);

    // ---- t = 0 ----
    stage_tile(ebase + (size_t)(tile0 + 1) * TCH, &embL[TCH], tid);
    asm volatile("s_waitcnt vmcnt(8)" ::: "memory");
    __builtin_amdgcn_s_barrier();
    tile_body(&embL[0], ctxw, out, s, (tile0 + 0) * TV, row, rx, wb);
    __builtin_amdgcn_s_barrier();
    // ---- t = 1 ----
    stage_tile(ebase + (size_t)(tile0 + 2) * TCH, &embL[0], tid);
    asm volatile("s_waitcnt vmcnt(12)" ::: "memory");
    __builtin_amdgcn_s_barrier();
    tile_body(&embL[TCH], ctxw, out, s, (tile0 + 1) * TV, row, rx, wb);
    __builtin_amdgcn_s_barrier();
    // ---- t = 2 ----
    stage_tile(ebase + (size_t)(tile0 + 3) * TCH, &embL[TCH], tid);
    asm volatile("s_waitcnt vmcnt(12)" ::: "memory");
    __builtin_amdgcn_s_barrier();
    tile_body(&embL[0], ctxw, out, s, (tile0 + 2) * TV, row, rx, wb);
    __builtin_amdgcn_s_barrier();
    // ---- t = 3 ----
    stage_tile(ebase + (size_t)(tile0 + 4) * TCH, &embL[0], tid);
    asm volatile("s_waitcnt vmcnt(12)" ::: "memory");
    __builtin_amdgcn_s_barrier();
    tile_body(&embL[TCH], ctxw, out, s, (tile0 + 3) * TV, row, rx, wb);
    __builtin_amdgcn_s_barrier();
    // ---- t = 4 ----
    asm volatile("s_waitcnt vmcnt(4)" ::: "memory");
    __builtin_amdgcn_s_barrier();
    tile_body(&embL[0], ctxw, out, s, (tile0 + 4) * TV, row, rx, wb);
}

extern "C" void kernel_launch(void* const* d_in, const int* in_sizes, int n_in,
                              void* d_out, int out_size, void* d_ws, size_t ws_size,
                              hipStream_t stream) {
    const int*   tokens  = (const int*)d_in[0];
    const float* scalars = (const float*)d_in[1];
    const float* wvecs   = (const float*)d_in[2];
    const float* emb     = (const float*)d_in[3];
    float*       out     = (float*)d_out;
    float*       ctx_n   = (float*)d_ws;   // S*B*D*4 = 393,216 bytes

    ctx_kernel<<<dim3(BB), dim3(64), 0, stream>>>(tokens, scalars, wvecs, ctx_n);

    dim3 grid(BPS, SS);   // (50, 48) = 2400 blocks, 256 threads each
    logits_kernel<<<grid, dim3(NT), 0, stream>>>(ctx_n, emb, out);
}

// Round 10
// 126.165 us; speedup vs baseline: 2.7040x; 1.4538x over previous
//
#include <hip/hip_runtime.h>

#define BB 16      // batch
#define SS 48      // seq len
#define VV 16000   // vocab
#define DD 128     // embed
#define TVR 128    // v-rows per block tile
#define NTH 256    // threads per block (4 waves)

constexpr float EPS   = 1e-8f;
constexpr float SCALE = 10.0f;

typedef __attribute__((ext_vector_type(8))) short bf16x8;
typedef __attribute__((ext_vector_type(4))) float f32x4;

__device__ __forceinline__ unsigned short f2bf_rne(float x) {
    union { float f; unsigned u; } v; v.f = x;
    unsigned r = v.u + 0x7fffu + ((v.u >> 16) & 1u);   // round-to-nearest-even
    return (unsigned short)(r >> 16);
}

// Kernel 1: per-batch causal prefix context, f32-normalized, emitted as BF16
// in A-fragment-friendly layout ctx_bf[S][B][D]. One block = one batch.
__global__ __launch_bounds__(64) void ctx_kernel(
    const int*      __restrict__ tokens,   // [B,S]
    const float*    __restrict__ scalars,  // [S,V]
    const float*    __restrict__ wvecs,    // [S,V,D]
    unsigned short* __restrict__ ctx_bf)   // [S,B,D] bf16
{
    const int b    = blockIdx.x;
    const int lane = threadIdx.x;  // 0..63

    float a[SS], w0[SS], w1[SS];
    #pragma unroll
    for (int s = 0; s < SS; ++s) {
        const int tok = tokens[b * SS + s];
        a[s] = scalars[(size_t)s * VV + tok];
        const float* wp = wvecs + ((size_t)s * VV + tok) * DD;
        w0[s] = wp[lane];
        w1[s] = wp[lane + 64];
    }

    float run0 = 0.f, run1 = 0.f;
    #pragma unroll
    for (int s = 0; s < SS; ++s) {
        float p = fmaf(run0, run0, run1 * run1);
        #pragma unroll
        for (int off = 32; off > 0; off >>= 1)
            p += __shfl_xor(p, off);
        const float denom = fmaxf(sqrtf(p), EPS);  // torch F.normalize semantics
        unsigned short* o = ctx_bf + ((size_t)s * BB + b) * DD;
        o[lane]      = f2bf_rne(run0 / denom);
        o[lane + 64] = f2bf_rne(run1 / denom);
        run0 = fmaf(a[s], w0[s], run0);   // position s contributes to positions > s
        run1 = fmaf(a[s], w1[s], run1);
    }
}

// Kernel 2: out[b,s,v] = SCALE * dot(ctx_n, emb[s,v,:]) / max(||emb[s,v,:]||,eps)
// via MFMA. Per block: stage one 128-row emb tile (f32, dense coalesced loads:
// each wave-inst covers 1 KB contiguous), convert to bf16 into swizzled LDS,
// compute row norms in f32 from the bf16 tile, then 8 mfma_16x16x32_bf16 per
// wave (A = ctx bf16 in registers, B = emb tile from LDS, one ds_read_b128
// per mfma). LDS/VALU/MFMA all ~10-17us chip-wide; HBM (~70us) is the wall.
__global__ __launch_bounds__(NTH) void logits_kernel(
    const unsigned short* __restrict__ ctx_bf,  // [S,B,D] bf16
    const float*          __restrict__ emb,     // [S,V,D] f32
    float*                __restrict__ out)     // [B,S,V] f32
{
    const int s    = blockIdx.y;
    const int v0   = blockIdx.x * TVR;
    const int tid  = threadIdx.x;      // 0..255
    const int lane = tid & 63;
    const int wv   = tid >> 6;         // wave 0..3

    __shared__ unsigned short eL[TVR * DD];  // 32 KB bf16 tile (swizzled 16B slots)
    __shared__ float nrm[TVR];               // row norms^2

    // ---- stage: dense coalesced f32 loads. flat float4 index f = tid + 256*i:
    // row = f>>5 = (tid>>5)+8i, float4-slot within row = tid&31.
    const float4* src = (const float4*)(emb + ((size_t)s * VV + v0) * DD);
    float4 g[16];
    #pragma unroll
    for (int i = 0; i < 16; ++i)
        g[i] = src[tid + i * NTH];

    // convert to bf16, write 8B granules; 16B-slot index XOR-swizzled by row&7
    const int slot4  = tid & 31;       // float4-slot (4 f32)
    const int slot16 = slot4 >> 1;     // 16B slot (8 bf16)
    const int hw     = slot4 & 1;      // half within 16B slot
    #pragma unroll
    for (int i = 0; i < 16; ++i) {
        const int row = (tid >> 5) + i * 8;
        const unsigned lo = ((unsigned)f2bf_rne(g[i].y) << 16) | f2bf_rne(g[i].x);
        const unsigned hi = ((unsigned)f2bf_rne(g[i].w) << 16) | f2bf_rne(g[i].z);
        unsigned* dst = (unsigned*)&eL[row * DD + ((slot16 ^ (row & 7)) << 3) + (hw << 2)];
        dst[0] = lo;
        dst[1] = hi;
    }
    __syncthreads();

    // ---- norms (f32 arithmetic over the bf16 tile): thread owns half a row
    {
        const int row = tid >> 1, half = tid & 1;
        float pn = 0.f;
        #pragma unroll
        for (int j = 0; j < 8; ++j) {
            const int s16 = half * 8 + j;
            const bf16x8 hh = *(const bf16x8*)&eL[row * DD + ((s16 ^ (row & 7)) << 3)];
            #pragma unroll
            for (int c = 0; c < 8; ++c) {
                union { unsigned u; float f; } t;
                t.u = ((unsigned)(unsigned short)hh[c]) << 16;
                pn = fmaf(t.f, t.f, pn);
            }
        }
        pn += __shfl_xor(pn, 1);       // partner half of same row
        if (half == 0) nrm[row] = pn;
    }
    __syncthreads();

    // ---- A-frags: ctx bf16 (4 KB per s, L2-resident, reused by 125 blocks).
    // A row (batch) = lane&15, k = (lane>>4)*8 + sl*32 + 0..7.
    bf16x8 afrag[4];
    {
        const unsigned short* cb = ctx_bf + ((size_t)s * BB + (lane & 15)) * DD + (lane >> 4) * 8;
        #pragma unroll
        for (int sl = 0; sl < 4; ++sl)
            afrag[sl] = *(const bf16x8*)(cb + sl * 32);
    }

    // ---- MFMA: wave wv owns 16-row groups 2wv and 2wv+1.
    // B col (v-row) = lane&15, k = (lane>>4)*8 + sl*32 + 0..7 -> 16B slot
    // q = sl*4 + (lane>>4), swizzled by row&7.
    f32x4 acc0 = {0.f, 0.f, 0.f, 0.f};
    f32x4 acc1 = {0.f, 0.f, 0.f, 0.f};
    const int r0 = (wv * 2) * 16 + (lane & 15);
    const int r1 = (wv * 2 + 1) * 16 + (lane & 15);
    #pragma unroll
    for (int sl = 0; sl < 4; ++sl) {
        const int q = sl * 4 + (lane >> 4);
        const bf16x8 b0 = *(const bf16x8*)&eL[r0 * DD + ((q ^ (r0 & 7)) << 3)];
        const bf16x8 b1 = *(const bf16x8*)&eL[r1 * DD + ((q ^ (r1 & 7)) << 3)];
        acc0 = __builtin_amdgcn_mfma_f32_16x16x32_bf16(afrag[sl], b0, acc0, 0, 0, 0);
        acc1 = __builtin_amdgcn_mfma_f32_16x16x32_bf16(afrag[sl], b1, acc1, 0, 0, 0);
    }

    // ---- store: D layout col(v) = lane&15, row(batch) = (lane>>4)*4 + reg
    const float f0 = SCALE / fmaxf(sqrtf(nrm[r0]), EPS);  // F.normalize semantics
    const float f1 = SCALE / fmaxf(sqrtf(nrm[r1]), EPS);
    const int va = v0 + r0;
    const int vb = v0 + r1;
    #pragma unroll
    for (int reg = 0; reg < 4; ++reg) {
        const int b = (lane >> 4) * 4 + reg;
        out[((size_t)b * SS + s) * VV + va] = acc0[reg] * f0;
        out[((size_t)b * SS + s) * VV + vb] = acc1[reg] * f1;
    }
}

extern "C" void kernel_launch(void* const* d_in, const int* in_sizes, int n_in,
                              void* d_out, int out_size, void* d_ws, size_t ws_size,
                              hipStream_t stream) {
    const int*      tokens  = (const int*)d_in[0];
    const float*    scalars = (const float*)d_in[1];
    const float*    wvecs   = (const float*)d_in[2];
    const float*    emb     = (const float*)d_in[3];
    float*          out     = (float*)d_out;
    unsigned short* ctx_bf  = (unsigned short*)d_ws;   // S*B*D*2 = 196,608 bytes

    ctx_kernel<<<dim3(BB), dim3(64), 0, stream>>>(tokens, scalars, wvecs, ctx_bf);

    dim3 grid(VV / TVR, SS);   // (125, 48) = 6000 blocks
    logits_kernel<<<grid, dim3(NTH), 0, stream>>>(ctx_bf, emb, out);
}